// Round 16
// baseline (313.182 us; speedup 1.0000x reference)
//
#include <hip/hip_runtime.h>
#include <hip/hip_bf16.h>

#define Dd 64
#define Hh 128
#define Ww 128
#define Cc 32

// block tile: 32d x 16h x 16w outputs; wave = 8d x 16h x 16w
#define BD 32
#define BH 16
#define BW 16
#define ZR (BD + 6)        // 38 staged z-planes
#define HR (BH + 6)        // 22 staged h-rows
#define NR (ZR * HR)       // 836 rows
#define RCOLS 24           // bf16 cols per row; col = w - w0 + 4 (left halo 4)
#define BLKROW 3
#define NBLK (NR * BLKROW) // 2508 16B blocks to stage

// A-fragment table: 49 7^3-planes x 14 windows + 9 3^3-planes x 10 windows
// + 1 shared all-zero entry. 777 entries x 16B = 12432 B in LDS.
// History: r12 global table = L2 write storm; r13 slot rotation = worse banks;
// r15 kh=6 inline-asm 16x16x16 = scheduler fence (-19%). Builtins only.
#define N7WIN 14
#define N3WIN 10
#define W3BASE (49 * N7WIN)          // 686
#define ZENT   (W3BASE + 9 * N3WIN) // 776
#define NENT   (ZENT + 1)           // 777

typedef __attribute__((ext_vector_type(8))) short short8;   // 8 bf16 (4 VGPR)
typedef __attribute__((ext_vector_type(4))) float floatx4;  // MFMA acc

static __device__ __forceinline__ unsigned pk2(float a, float b) {
    union { __hip_bfloat162 h; unsigned u; } cv;
    cv.h = __float22bfloat162_rn(make_float2(a, b));   // v_cvt_pk_bf16_f32 (RNE)
    return cv.u;
}

__global__ __launch_bounds__(256, 3) void replk_mfma(
    const float* __restrict__ x,
    const float* __restrict__ w7, const float* __restrict__ w3, const float* __restrict__ w1,
    const float* __restrict__ g7, const float* __restrict__ b7, const float* __restrict__ m7, const float* __restrict__ v7,
    const float* __restrict__ g3, const float* __restrict__ b3, const float* __restrict__ m3, const float* __restrict__ v3,
    const float* __restrict__ g1, const float* __restrict__ b1, const float* __restrict__ m1, const float* __restrict__ v1,
    float* __restrict__ out)
{
    __shared__ __align__(16) unsigned short tile[NR * RCOLS];  // 40128 B
    __shared__ __align__(16) unsigned short wtab[NENT * 8];    // 12432 B
    // 52560 raw -> 53248 granule; x3 = 159744 <= 160 KiB -> 3 blocks/CU

    const int tid = threadIdx.x;

    // XCD-aware swizzle: 8192 blocks, 8 XCDs, 1024 contiguous per XCD.
    const unsigned lid = blockIdx.x;
    const unsigned nl = (lid & 7u) * 1024u + (lid >> 3);
    const int bx = nl & 127;
    const int slab = nl >> 7;
    const int c = slab & 31;
    const int nb = slab >> 5;
    const int w0 = (bx & 7) * BW;
    const int h0 = ((bx >> 3) & 7) * BH;
    const int d0 = (bx >> 6) * BD;

    const float* xc = x + (size_t)(nb * Cc + c) * (Dd * Hh * Ww);

    // ---- build A-fragment table in LDS (cvt_pk packing) ----
    for (int e = tid; e < NENT; e += 256) {
        float v[8];
#pragma unroll
        for (int j = 0; j < 8; j++) {
            float vv = 0.f;
            if (e < W3BASE) {
                int pl = e / N7WIN, a = e - pl * N7WIN;
                int t = a + j - 7;
                if ((unsigned)t < 7u)
                    vv = w7[c * 343 + (pl / 7) * 49 + (pl % 7) * 7 + t];
            } else if (e < ZENT) {
                int e2 = e - W3BASE;
                int p3 = e2 / N3WIN, a = e2 - p3 * N3WIN;
                int t = a + j - 7;
                if ((unsigned)t < 3u)
                    vv = w3[c * 27 + (p3 / 3) * 9 + (p3 % 3) * 3 + t];
            }
            v[j] = vv;
        }
        uint4 pk;
        pk.x = pk2(v[0], v[1]);
        pk.y = pk2(v[2], v[3]);
        pk.z = pk2(v[4], v[5]);
        pk.w = pk2(v[6], v[7]);
        *(uint4*)&wtab[e * 8] = pk;
    }

    // ---- stage input tile fp32 -> bf16, division-free incremental indices ----
    {
        int s = tid;
        int R = tid / 3;
        int bl = tid - R * 3;
        int zi = R / HR;
        int hr = R - zi * HR;
#pragma unroll
        for (int it = 0; it < 10; it++) {
            if (s < NBLK) {
                int gz = d0 - 3 + zi, gh = h0 - 3 + hr, gw0 = w0 - 4 + bl * 8;
                float v[8];
#pragma unroll
                for (int j = 0; j < 8; j++) v[j] = 0.f;
                if ((unsigned)gz < (unsigned)Dd && (unsigned)gh < (unsigned)Hh) {
                    const float* src = xc + ((size_t)gz * Hh + gh) * Ww + gw0;
                    if (gw0 >= 0 && gw0 + 8 <= Ww) {
                        float4 a = *(const float4*)src;
                        float4 b = *(const float4*)(src + 4);
                        v[0] = a.x; v[1] = a.y; v[2] = a.z; v[3] = a.w;
                        v[4] = b.x; v[5] = b.y; v[6] = b.z; v[7] = b.w;
                    } else {
#pragma unroll
                        for (int j = 0; j < 8; j++) {
                            int gw = gw0 + j;
                            if ((unsigned)gw < (unsigned)Ww) v[j] = src[j];
                        }
                    }
                }
                uint4 pk;
                pk.x = pk2(v[0], v[1]);
                pk.y = pk2(v[2], v[3]);
                pk.z = pk2(v[4], v[5]);
                pk.w = pk2(v[6], v[7]);
                *(uint4*)&tile[R * RCOLS + bl * 8] = pk;
            }
            // step +256: 256 = 3*85+1; 85 = 3*22+19 (HR=22)
            s += 256;
            bl += 1; R += 85; zi += 3; hr += 19;
            if (bl == 3) { bl = 0; R += 1; hr += 1; }
            if (hr >= HR) { hr -= HR; zi += 1; }
        }
    }

    // BN constants (wave-uniform)
    const float eps = 1e-5f;
    const float iv7 = g7[c] / sqrtf(v7[c] + eps);
    const float bb7 = b7[c] - m7[c] * iv7;
    const float iv3 = g3[c] / sqrtf(v3[c] + eps);
    const float bb3 = b3[c] - m3[c] * iv3;
    const float iv1 = g1[c] / sqrtf(v1[c] + eps);
    const float bb1 = b1[c] - m1[c] * iv1;
    const float s1 = w1[c] * iv1;

    __syncthreads();

    const int lane = tid & 63;
    const int wave = tid >> 6;
    const int q = lane & 15;          // m (A) / n (B,C,D)
    const int p = lane >> 4;
    const int khp = p >> 1;           // kh within pair
    const int kb  = p & 1;            // wc 16B-block
    const int ddl = q >> 3;           // d within M-pair (A side)
    const int mwq = q & 7;            // w within M (A side)
    const int zbase = wave * 8;       // wave owns d-outputs [zbase, zbase+8)

    const int a7 = 8 * kb - mwq + 6;  // 7^3 window (valid [0,14))
    const int a3 = a7 - 2;            // 3^3 window (valid [0,10))
    const short8* wf = (const short8*)wtab;

    floatx4 acc7[4][2], acc3[4][2];
#pragma unroll
    for (int i = 0; i < 4; i++)
#pragma unroll
        for (int wh = 0; wh < 2; wh++) { acc7[i][wh] = (floatx4)0.f; acc3[i][wh] = (floatx4)0.f; }

    // ---- khg-outer loop: kh-pairs {0,1}{2,3}{4,5}{6,-}; 3^3 shares B of khg 1,2 ----
#pragma unroll 1
    for (int khg = 0; khg < 4; khg++) {
        const int kh = 2 * khg + khp;                       // 0..7 (7 = zero)
        const bool ok7 = ((unsigned)a7 < 14u) && (kh <= 6);
        const int cb7 = ok7 ? (kh * 14 + a7 - ddl * 98) : (int)ZENT;
        const int st7 = ok7 ? 98 : 0;
        short8 A7g[8];
#pragma unroll
        for (int rz = 0; rz < 8; rz++) {
            int idx = cb7 + rz * st7;
            if (rz == 0) idx = (ddl == 0 && ok7) ? idx : (int)ZENT;  // kd=-1 lanes
            if (rz == 7) idx = (ddl == 1 && ok7) ? idx : (int)ZENT;  // kd=7 lanes
            A7g[rz] = wf[idx];
        }

        const bool has3 = (khg == 1) || (khg == 2);
        short8 A3g[4] = {};
        if (has3) {
            const int kh3 = 2 * (khg - 1) + khp;            // 0..3 (3 = zero)
            const bool ok3 = ((unsigned)a3 < 10u) && (kh3 <= 2);
            const int cb3 = ok3 ? (W3BASE + kh3 * 10 + a3 - ddl * 30) : (int)ZENT;
            const int st3 = ok3 ? 30 : 0;
#pragma unroll
            for (int rz = 0; rz < 4; rz++) {
                int idx = cb3 + rz * st3;
                if (rz == 0) idx = (ddl == 0 && ok3) ? idx : (int)ZENT;
                if (rz == 3) idx = (ddl == 1 && ok3) ? idx : (int)ZENT;
                A3g[rz] = wf[idx];
            }
        }

        // kh=7 lanes (khg=3, khp=1) have zero A: clamp their B row to kh=6's.
        const int rowadd = (khg == 3) ? 6 : (2 * khg + khp);

#pragma unroll
        for (int zi = 0; zi < 14; zi++) {
            const int R = (zbase + zi) * HR + q + rowadd;
            const unsigned short* bp = &tile[R * RCOLS + 8 * kb];
            short8 B0 = *(const short8*)bp;
            short8 B1 = *(const short8*)(bp + 8);
#pragma unroll
            for (int ddg = 0; ddg < 4; ddg++) {
                const int rz = zi - 2 * ddg;
                if (rz >= 0 && rz < 8) {
                    acc7[ddg][0] = __builtin_amdgcn_mfma_f32_16x16x32_bf16(
                        A7g[rz], B0, acc7[ddg][0], 0, 0, 0);
                    acc7[ddg][1] = __builtin_amdgcn_mfma_f32_16x16x32_bf16(
                        A7g[rz], B1, acc7[ddg][1], 0, 0, 0);
                }
            }
            if (has3) {
#pragma unroll
                for (int ddg = 0; ddg < 4; ddg++) {
                    const int rz3 = zi - 2 - 2 * ddg;
                    if (rz3 >= 0 && rz3 < 4) {
                        acc3[ddg][0] = __builtin_amdgcn_mfma_f32_16x16x32_bf16(
                            A3g[rz3], B0, acc3[ddg][0], 0, 0, 0);
                        acc3[ddg][1] = __builtin_amdgcn_mfma_f32_16x16x32_bf16(
                            A3g[rz3], B1, acc3[ddg][1], 0, 0, 0);
                    }
                }
            }
        }
    }

    // ---- epilogue: C/D col n=q (h), row m=4p+r; residual x from LDS tile ----
#pragma unroll
    for (int ddg = 0; ddg < 4; ddg++) {
#pragma unroll
        for (int wh = 0; wh < 2; wh++) {
            const int d = d0 + zbase + 2 * ddg + khp;
            const int Rr = (zbase + 2 * ddg + khp + 3) * HR + (q + 3);
            uint2 u = *(const uint2*)&tile[Rr * RCOLS + 8 * wh + 4 * kb + 4];
            float xr[4];
            xr[0] = __builtin_bit_cast(float, u.x << 16);
            xr[1] = __builtin_bit_cast(float, u.x & 0xffff0000u);
            xr[2] = __builtin_bit_cast(float, u.y << 16);
            xr[3] = __builtin_bit_cast(float, u.y & 0xffff0000u);

            size_t off = ((size_t)(nb * Cc + c) * Dd + d) * (Hh * Ww)
                       + (size_t)(h0 + q) * Ww + w0 + 8 * wh + 4 * kb;
            float o[4];
#pragma unroll
            for (int r = 0; r < 4; r++) {
                float y7 = fmaxf(fmaf(acc7[ddg][wh][r], iv7, bb7), 0.f);
                float y3 = fmaxf(fmaf(acc3[ddg][wh][r], iv3, bb3), 0.f);
                float y1 = fmaxf(fmaf(xr[r], s1, bb1), 0.f);
                o[r] = fmaxf(xr[r] + y7 + y3 + y1, 0.f);
            }
            *(float4*)(out + off) = make_float4(o[0], o[1], o[2], o[3]);
        }
    }
}

extern "C" void kernel_launch(void* const* d_in, const int* in_sizes, int n_in,
                              void* d_out, int out_size, void* d_ws, size_t ws_size,
                              hipStream_t stream) {
    const float* x  = (const float*)d_in[0];
    const float* w7 = (const float*)d_in[1];
    const float* w3 = (const float*)d_in[2];
    const float* w1 = (const float*)d_in[3];
    const float* g7 = (const float*)d_in[4];
    const float* b7 = (const float*)d_in[5];
    const float* m7 = (const float*)d_in[6];
    const float* v7 = (const float*)d_in[7];
    const float* g3 = (const float*)d_in[8];
    const float* b3 = (const float*)d_in[9];
    const float* m3 = (const float*)d_in[10];
    const float* v3 = (const float*)d_in[11];
    const float* g1 = (const float*)d_in[12];
    const float* b1 = (const float*)d_in[13];
    const float* m1 = (const float*)d_in[14];
    const float* v1 = (const float*)d_in[15];
    float* out = (float*)d_out;

    dim3 grid(8192);   // 1-D; kernel swizzles to (slab, tile) XCD-contiguously
    dim3 block(256);
    hipLaunchKernelGGL(replk_mfma, grid, block, 0, stream,
                       x, w7, w3, w1, g7, b7, m7, v7, g3, b3, m3, v3,
                       g1, b1, m1, v1, out);
}

// Round 17
// 280.030 us; speedup vs baseline: 1.1184x; 1.1184x over previous
//
#include <hip/hip_runtime.h>
#include <hip/hip_bf16.h>

#define Dd 64
#define Hh 128
#define Ww 128
#define Cc 32

// block tile: 32d x 16h x 16w outputs; wave = 8d x 16h x 16w
#define BD 32
#define BH 16
#define BW 16
#define ZR (BD + 6)        // 38 staged z-planes
#define HR (BH + 6)        // 22 staged h-rows
#define NR (ZR * HR)       // 836 rows
#define RCOLS 24           // bf16 cols per row; col = w - w0 + 4 (left halo 4)
#define BLKROW 3
#define NBLK (NR * BLKROW) // 2508 16B blocks to stage

// A-fragment table: 49 7^3-planes x 14 windows + 9 3^3-planes x 10 windows
// + 1 shared all-zero entry. 777 entries x 16B = 12432 B in LDS.
// History: r12 global table = L2 write storm; r13 slot rotation = worse banks;
// r15/r16 "div-free" staging serialized the 10 staging loads (-50us) — keep
// division-based independent indices; builtin MFMAs only (no inline asm).
#define N7WIN 14
#define N3WIN 10
#define W3BASE (49 * N7WIN)          // 686
#define ZENT   (W3BASE + 9 * N3WIN) // 776
#define NENT   (ZENT + 1)           // 777

typedef __attribute__((ext_vector_type(8))) short short8;   // 8 bf16 (4 VGPR)
typedef __attribute__((ext_vector_type(4))) float floatx4;  // MFMA acc

static __device__ __forceinline__ unsigned short f2bf(float f) {
    unsigned u = __builtin_bit_cast(unsigned, f);
    u += 0x7fffu + ((u >> 16) & 1u);   // RNE
    return (unsigned short)(u >> 16);
}

static __device__ __forceinline__ unsigned pk2(float a, float b) {
    union { __hip_bfloat162 h; unsigned u; } cv;
    cv.h = __float22bfloat162_rn(make_float2(a, b));   // v_cvt_pk_bf16_f32
    return cv.u;
}

__global__ __launch_bounds__(256, 3) void replk_mfma(
    const float* __restrict__ x,
    const float* __restrict__ w7, const float* __restrict__ w3, const float* __restrict__ w1,
    const float* __restrict__ g7, const float* __restrict__ b7, const float* __restrict__ m7, const float* __restrict__ v7,
    const float* __restrict__ g3, const float* __restrict__ b3, const float* __restrict__ m3, const float* __restrict__ v3,
    const float* __restrict__ g1, const float* __restrict__ b1, const float* __restrict__ m1, const float* __restrict__ v1,
    float* __restrict__ out)
{
    __shared__ __align__(16) unsigned short tile[NR * RCOLS];  // 40128 B
    __shared__ __align__(16) unsigned short wtab[NENT * 8];    // 12432 B
    // 52560 raw -> 53248 granule; x3 = 159744 <= 160 KiB -> 3 blocks/CU

    const int tid = threadIdx.x;

    // XCD-aware swizzle: 8192 blocks, 8 XCDs, 1024 contiguous per XCD.
    const unsigned lid = blockIdx.x;
    const unsigned nl = (lid & 7u) * 1024u + (lid >> 3);
    const int bx = nl & 127;
    const int slab = nl >> 7;
    const int c = slab & 31;
    const int nb = slab >> 5;
    const int w0 = (bx & 7) * BW;
    const int h0 = ((bx >> 3) & 7) * BH;
    const int d0 = (bx >> 6) * BD;

    const float* xc = x + (size_t)(nb * Cc + c) * (Dd * Hh * Ww);

    // ---- build A-fragment table in LDS (r10/r11 layout, verified) ----
    for (int e = tid; e < NENT; e += 256) {
        unsigned short h8[8];
#pragma unroll
        for (int j = 0; j < 8; j++) {
            float v = 0.f;
            if (e < W3BASE) {
                int pl = e / N7WIN, a = e - pl * N7WIN;
                int t = a + j - 7;
                if ((unsigned)t < 7u)
                    v = w7[c * 343 + (pl / 7) * 49 + (pl % 7) * 7 + t];
            } else if (e < ZENT) {
                int e2 = e - W3BASE;
                int p3 = e2 / N3WIN, a = e2 - p3 * N3WIN;
                int t = a + j - 7;
                if ((unsigned)t < 3u)
                    v = w3[c * 27 + (p3 / 3) * 9 + (p3 % 3) * 3 + t];
            }
            h8[j] = f2bf(v);
        }
        uint4 pk;
        pk.x = (unsigned)h8[0] | ((unsigned)h8[1] << 16);
        pk.y = (unsigned)h8[2] | ((unsigned)h8[3] << 16);
        pk.z = (unsigned)h8[4] | ((unsigned)h8[5] << 16);
        pk.w = (unsigned)h8[6] | ((unsigned)h8[7] << 16);
        *(uint4*)&wtab[e * 8] = pk;
    }

    // ---- stage input tile fp32 -> bf16 (cvt_pk), division-based indices ----
    // (divisions keep the 10 iterations' addresses INDEPENDENT so all loads
    //  issue up front — r15/r16's incremental chain serialized them, -50us)
#pragma unroll
    for (int it = 0; it < 10; it++) {
        int s = tid + it * 256;
        if (s < NBLK) {
            int R = s / BLKROW, bl = s - R * BLKROW;
            int zi = R / HR, hr = R - zi * HR;
            int gz = d0 - 3 + zi, gh = h0 - 3 + hr, gw0 = w0 - 4 + bl * 8;
            float v[8];
#pragma unroll
            for (int j = 0; j < 8; j++) v[j] = 0.f;
            if ((unsigned)gz < (unsigned)Dd && (unsigned)gh < (unsigned)Hh) {
                const float* src = xc + ((size_t)gz * Hh + gh) * Ww + gw0;
                if (gw0 >= 0 && gw0 + 8 <= Ww) {
                    float4 a = *(const float4*)src;
                    float4 b = *(const float4*)(src + 4);
                    v[0] = a.x; v[1] = a.y; v[2] = a.z; v[3] = a.w;
                    v[4] = b.x; v[5] = b.y; v[6] = b.z; v[7] = b.w;
                } else {
#pragma unroll
                    for (int j = 0; j < 8; j++) {
                        int gw = gw0 + j;
                        if ((unsigned)gw < (unsigned)Ww) v[j] = src[j];
                    }
                }
            }
            uint4 pk;
            pk.x = pk2(v[0], v[1]);
            pk.y = pk2(v[2], v[3]);
            pk.z = pk2(v[4], v[5]);
            pk.w = pk2(v[6], v[7]);
            *(uint4*)&tile[R * RCOLS + bl * 8] = pk;
        }
    }

    // BN constants (wave-uniform)
    const float eps = 1e-5f;
    const float iv7 = g7[c] / sqrtf(v7[c] + eps);
    const float bb7 = b7[c] - m7[c] * iv7;
    const float iv3 = g3[c] / sqrtf(v3[c] + eps);
    const float bb3 = b3[c] - m3[c] * iv3;
    const float iv1 = g1[c] / sqrtf(v1[c] + eps);
    const float bb1 = b1[c] - m1[c] * iv1;
    const float s1 = w1[c] * iv1;

    __syncthreads();

    const int lane = tid & 63;
    const int wave = tid >> 6;
    const int q = lane & 15;          // m (A) / n (B,C,D)
    const int p = lane >> 4;
    const int khp = p >> 1;           // kh within pair
    const int kb  = p & 1;            // wc 16B-block
    const int ddl = q >> 3;           // d within M-pair (A side)
    const int mwq = q & 7;            // w within M (A side)
    const int zbase = wave * 8;       // wave owns d-outputs [zbase, zbase+8)

    const int a7 = 8 * kb - mwq + 6;  // 7^3 window (valid [0,14))
    const int a3 = a7 - 2;            // 3^3 window (valid [0,10))
    const short8* wf = (const short8*)wtab;

    floatx4 acc7[4][2], acc3[4][2];
#pragma unroll
    for (int i = 0; i < 4; i++)
#pragma unroll
        for (int wh = 0; wh < 2; wh++) { acc7[i][wh] = (floatx4)0.f; acc3[i][wh] = (floatx4)0.f; }

    // ---- khg-outer loop, FULLY UNROLLED (r17): lets the scheduler overlap
    //      pass k+1's A-fragment loads under pass k's MFMA tail ----
#pragma unroll
    for (int khg = 0; khg < 4; khg++) {
        const int kh = 2 * khg + khp;                       // 0..7 (7 = zero)
        const bool ok7 = ((unsigned)a7 < 14u) && (kh <= 6);
        const int cb7 = ok7 ? (kh * 14 + a7 - ddl * 98) : (int)ZENT;
        const int st7 = ok7 ? 98 : 0;
        short8 A7g[8];
#pragma unroll
        for (int rz = 0; rz < 8; rz++) {
            int idx = cb7 + rz * st7;
            if (rz == 0) idx = (ddl == 0 && ok7) ? idx : (int)ZENT;  // kd=-1 lanes
            if (rz == 7) idx = (ddl == 1 && ok7) ? idx : (int)ZENT;  // kd=7 lanes
            A7g[rz] = wf[idx];
        }

        const bool has3 = (khg == 1) || (khg == 2);
        short8 A3g[4] = {};
        if (has3) {
            const int kh3 = 2 * (khg - 1) + khp;            // 0..3 (3 = zero)
            const bool ok3 = ((unsigned)a3 < 10u) && (kh3 <= 2);
            const int cb3 = ok3 ? (W3BASE + kh3 * 10 + a3 - ddl * 30) : (int)ZENT;
            const int st3 = ok3 ? 30 : 0;
#pragma unroll
            for (int rz = 0; rz < 4; rz++) {
                int idx = cb3 + rz * st3;
                if (rz == 0) idx = (ddl == 0 && ok3) ? idx : (int)ZENT;
                if (rz == 3) idx = (ddl == 1 && ok3) ? idx : (int)ZENT;
                A3g[rz] = wf[idx];
            }
        }

        // kh=7 lanes (khg=3, khp=1) have zero A: clamp their B row to kh=6's.
        const int rowadd = (khg == 3) ? 6 : (2 * khg + khp);

#pragma unroll
        for (int zi = 0; zi < 14; zi++) {
            const int R = (zbase + zi) * HR + q + rowadd;
            const unsigned short* bp = &tile[R * RCOLS + 8 * kb];
            short8 B0 = *(const short8*)bp;
            short8 B1 = *(const short8*)(bp + 8);
#pragma unroll
            for (int ddg = 0; ddg < 4; ddg++) {
                const int rz = zi - 2 * ddg;
                if (rz >= 0 && rz < 8) {
                    acc7[ddg][0] = __builtin_amdgcn_mfma_f32_16x16x32_bf16(
                        A7g[rz], B0, acc7[ddg][0], 0, 0, 0);
                    acc7[ddg][1] = __builtin_amdgcn_mfma_f32_16x16x32_bf16(
                        A7g[rz], B1, acc7[ddg][1], 0, 0, 0);
                }
            }
            if (has3) {
#pragma unroll
                for (int ddg = 0; ddg < 4; ddg++) {
                    const int rz3 = zi - 2 - 2 * ddg;
                    if (rz3 >= 0 && rz3 < 4) {
                        acc3[ddg][0] = __builtin_amdgcn_mfma_f32_16x16x32_bf16(
                            A3g[rz3], B0, acc3[ddg][0], 0, 0, 0);
                        acc3[ddg][1] = __builtin_amdgcn_mfma_f32_16x16x32_bf16(
                            A3g[rz3], B1, acc3[ddg][1], 0, 0, 0);
                    }
                }
            }
        }
    }

    // ---- epilogue: C/D col n=q (h), row m=4p+r; residual x from LDS tile ----
#pragma unroll
    for (int ddg = 0; ddg < 4; ddg++) {
#pragma unroll
        for (int wh = 0; wh < 2; wh++) {
            const int d = d0 + zbase + 2 * ddg + khp;
            const int Rr = (zbase + 2 * ddg + khp + 3) * HR + (q + 3);
            uint2 u = *(const uint2*)&tile[Rr * RCOLS + 8 * wh + 4 * kb + 4];
            float xr[4];
            xr[0] = __builtin_bit_cast(float, u.x << 16);
            xr[1] = __builtin_bit_cast(float, u.x & 0xffff0000u);
            xr[2] = __builtin_bit_cast(float, u.y << 16);
            xr[3] = __builtin_bit_cast(float, u.y & 0xffff0000u);

            size_t off = ((size_t)(nb * Cc + c) * Dd + d) * (Hh * Ww)
                       + (size_t)(h0 + q) * Ww + w0 + 8 * wh + 4 * kb;
            float o[4];
#pragma unroll
            for (int r = 0; r < 4; r++) {
                float y7 = fmaxf(fmaf(acc7[ddg][wh][r], iv7, bb7), 0.f);
                float y3 = fmaxf(fmaf(acc3[ddg][wh][r], iv3, bb3), 0.f);
                float y1 = fmaxf(fmaf(xr[r], s1, bb1), 0.f);
                o[r] = fmaxf(xr[r] + y7 + y3 + y1, 0.f);
            }
            *(float4*)(out + off) = make_float4(o[0], o[1], o[2], o[3]);
        }
    }
}

extern "C" void kernel_launch(void* const* d_in, const int* in_sizes, int n_in,
                              void* d_out, int out_size, void* d_ws, size_t ws_size,
                              hipStream_t stream) {
    const float* x  = (const float*)d_in[0];
    const float* w7 = (const float*)d_in[1];
    const float* w3 = (const float*)d_in[2];
    const float* w1 = (const float*)d_in[3];
    const float* g7 = (const float*)d_in[4];
    const float* b7 = (const float*)d_in[5];
    const float* m7 = (const float*)d_in[6];
    const float* v7 = (const float*)d_in[7];
    const float* g3 = (const float*)d_in[8];
    const float* b3 = (const float*)d_in[9];
    const float* m3 = (const float*)d_in[10];
    const float* v3 = (const float*)d_in[11];
    const float* g1 = (const float*)d_in[12];
    const float* b1 = (const float*)d_in[13];
    const float* m1 = (const float*)d_in[14];
    const float* v1 = (const float*)d_in[15];
    float* out = (float*)d_out;

    dim3 grid(8192);   // 1-D; kernel swizzles to (slab, tile) XCD-contiguously
    dim3 block(256);
    hipLaunchKernelGGL(replk_mfma, grid, block, 0, stream,
                       x, w7, w3, w1, g7, b7, m7, v7, g3, b3, m3, v3,
                       g1, b1, m1, v1, out);
}

// Round 18
// 260.152 us; speedup vs baseline: 1.2038x; 1.0764x over previous
//
#include <hip/hip_runtime.h>
#include <hip/hip_bf16.h>

#define Dd 64
#define Hh 128
#define Ww 128
#define Cc 32

// block tile: 32d x 16h x 16w outputs; wave = 8d x 16h x 16w
#define BD 32
#define BH 16
#define BW 16
#define ZR (BD + 6)        // 38 staged z-planes
#define HR (BH + 6)        // 22 staged h-rows
#define NR (ZR * HR)       // 836 rows
#define RCOLS 24           // bf16 cols per row; col = w - w0 + 4 (left halo 4)
#define BLKROW 3
#define NBLK (NR * BLKROW) // 2508 16B blocks to stage

// A-fragment table: 49 7^3-planes x 14 windows + 9 3^3-planes x 10 windows
// + 1 shared all-zero entry. 777 entries x 16B = 12432 B in LDS.
// Measured dead ends (do not revisit): r12 global wtab = L2 write storm
// (6.3x); r13 slot rotation = worse banks (uniform 2-way is free); r15/r16
// incremental staging indices = serialized loads (-50us); r15 inline-asm
// MFMA = scheduler fence; r17 full khg unroll = scratch spill (+112MB writes).
#define N7WIN 14
#define N3WIN 10
#define W3BASE (49 * N7WIN)          // 686
#define ZENT   (W3BASE + 9 * N3WIN) // 776
#define NENT   (ZENT + 1)           // 777

typedef __attribute__((ext_vector_type(8))) short short8;   // 8 bf16 (4 VGPR)
typedef __attribute__((ext_vector_type(4))) float floatx4;  // MFMA acc

static __device__ __forceinline__ unsigned short f2bf(float f) {
    unsigned u = __builtin_bit_cast(unsigned, f);
    u += 0x7fffu + ((u >> 16) & 1u);   // RNE
    return (unsigned short)(u >> 16);
}

static __device__ __forceinline__ unsigned pk2(float a, float b) {
    union { __hip_bfloat162 h; unsigned u; } cv;
    cv.h = __float22bfloat162_rn(make_float2(a, b));   // v_cvt_pk_bf16_f32
    return cv.u;
}

__global__ __launch_bounds__(256, 3) void replk_mfma(
    const float* __restrict__ x,
    const float* __restrict__ w7, const float* __restrict__ w3, const float* __restrict__ w1,
    const float* __restrict__ g7, const float* __restrict__ b7, const float* __restrict__ m7, const float* __restrict__ v7,
    const float* __restrict__ g3, const float* __restrict__ b3, const float* __restrict__ m3, const float* __restrict__ v3,
    const float* __restrict__ g1, const float* __restrict__ b1, const float* __restrict__ m1, const float* __restrict__ v1,
    float* __restrict__ out)
{
    __shared__ __align__(16) unsigned short tile[NR * RCOLS];  // 40128 B
    __shared__ __align__(16) unsigned short wtab[NENT * 8];    // 12432 B
    // 52560 raw -> 53248 granule; x3 = 159744 <= 160 KiB -> 3 blocks/CU

    const int tid = threadIdx.x;

    // XCD-aware swizzle: 8192 blocks, 8 XCDs, 1024 contiguous per XCD.
    const unsigned lid = blockIdx.x;
    const unsigned nl = (lid & 7u) * 1024u + (lid >> 3);
    const int bx = nl & 127;
    const int slab = nl >> 7;
    const int c = slab & 31;
    const int nb = slab >> 5;
    const int w0 = (bx & 7) * BW;
    const int h0 = ((bx >> 3) & 7) * BH;
    const int d0 = (bx >> 6) * BD;

    const float* xc = x + (size_t)(nb * Cc + c) * (Dd * Hh * Ww);

    // ---- build A-fragment table in LDS (r10/r11 layout, verified) ----
    for (int e = tid; e < NENT; e += 256) {
        unsigned short h8[8];
#pragma unroll
        for (int j = 0; j < 8; j++) {
            float v = 0.f;
            if (e < W3BASE) {
                int pl = e / N7WIN, a = e - pl * N7WIN;
                int t = a + j - 7;
                if ((unsigned)t < 7u)
                    v = w7[c * 343 + (pl / 7) * 49 + (pl % 7) * 7 + t];
            } else if (e < ZENT) {
                int e2 = e - W3BASE;
                int p3 = e2 / N3WIN, a = e2 - p3 * N3WIN;
                int t = a + j - 7;
                if ((unsigned)t < 3u)
                    v = w3[c * 27 + (p3 / 3) * 9 + (p3 % 3) * 3 + t];
            }
            h8[j] = f2bf(v);
        }
        uint4 pk;
        pk.x = (unsigned)h8[0] | ((unsigned)h8[1] << 16);
        pk.y = (unsigned)h8[2] | ((unsigned)h8[3] << 16);
        pk.z = (unsigned)h8[4] | ((unsigned)h8[5] << 16);
        pk.w = (unsigned)h8[6] | ((unsigned)h8[7] << 16);
        *(uint4*)&wtab[e * 8] = pk;
    }

    // ---- stage input tile fp32 -> bf16 (cvt_pk), division-based indices ----
    // (divisions keep the 10 iterations' addresses INDEPENDENT so all loads
    //  issue up front — incremental chains serialize them)
#pragma unroll
    for (int it = 0; it < 10; it++) {
        int s = tid + it * 256;
        if (s < NBLK) {
            int R = s / BLKROW, bl = s - R * BLKROW;
            int zi = R / HR, hr = R - zi * HR;
            int gz = d0 - 3 + zi, gh = h0 - 3 + hr, gw0 = w0 - 4 + bl * 8;
            float v[8];
#pragma unroll
            for (int j = 0; j < 8; j++) v[j] = 0.f;
            if ((unsigned)gz < (unsigned)Dd && (unsigned)gh < (unsigned)Hh) {
                const float* src = xc + ((size_t)gz * Hh + gh) * Ww + gw0;
                if (gw0 >= 0 && gw0 + 8 <= Ww) {
                    float4 a = *(const float4*)src;
                    float4 b = *(const float4*)(src + 4);
                    v[0] = a.x; v[1] = a.y; v[2] = a.z; v[3] = a.w;
                    v[4] = b.x; v[5] = b.y; v[6] = b.z; v[7] = b.w;
                } else {
#pragma unroll
                    for (int j = 0; j < 8; j++) {
                        int gw = gw0 + j;
                        if ((unsigned)gw < (unsigned)Ww) v[j] = src[j];
                    }
                }
            }
            uint4 pk;
            pk.x = pk2(v[0], v[1]);
            pk.y = pk2(v[2], v[3]);
            pk.z = pk2(v[4], v[5]);
            pk.w = pk2(v[6], v[7]);
            *(uint4*)&tile[R * RCOLS + bl * 8] = pk;
        }
    }

    // BN constants (wave-uniform)
    const float eps = 1e-5f;
    const float iv7 = g7[c] / sqrtf(v7[c] + eps);
    const float bb7 = b7[c] - m7[c] * iv7;
    const float iv3 = g3[c] / sqrtf(v3[c] + eps);
    const float bb3 = b3[c] - m3[c] * iv3;
    const float iv1 = g1[c] / sqrtf(v1[c] + eps);
    const float bb1 = b1[c] - m1[c] * iv1;
    const float s1 = w1[c] * iv1;

    __syncthreads();

    const int lane = tid & 63;
    const int wave = tid >> 6;
    const int q = lane & 15;          // m (A) / n (B,C,D)
    const int p = lane >> 4;
    const int khp = p >> 1;           // kh within pair
    const int kb  = p & 1;            // wc 16B-block
    const int ddl = q >> 3;           // d within M-pair (A side)
    const int mwq = q & 7;            // w within M (A side)
    const int zbase = wave * 8;       // wave owns d-outputs [zbase, zbase+8)

    const int a7 = 8 * kb - mwq + 6;  // 7^3 window (valid [0,14))
    const int a3 = a7 - 2;            // 3^3 window (valid [0,10))
    const short8* wf = (const short8*)wtab;

    floatx4 acc7[4][2], acc3[4][2];
#pragma unroll
    for (int i = 0; i < 4; i++)
#pragma unroll
        for (int wh = 0; wh < 2; wh++) { acc7[i][wh] = (floatx4)0.f; acc3[i][wh] = (floatx4)0.f; }

    // ---- khg-outer loop (NOT unrolled — r17's full unroll spilled):
    //      kh-pairs {0,1}{2,3}{4,5}{6,-}; 3^3 shares B of khg 1,2 ----
#pragma unroll 1
    for (int khg = 0; khg < 4; khg++) {
        const int kh = 2 * khg + khp;                       // 0..7 (7 = zero)
        const bool ok7 = ((unsigned)a7 < 14u) && (kh <= 6);
        const int cb7 = ok7 ? (kh * 14 + a7 - ddl * 98) : (int)ZENT;
        const int st7 = ok7 ? 98 : 0;
        short8 A7g[8];
#pragma unroll
        for (int rz = 0; rz < 8; rz++) {
            int idx = cb7 + rz * st7;
            if (rz == 0) idx = (ddl == 0 && ok7) ? idx : (int)ZENT;  // kd=-1 lanes
            if (rz == 7) idx = (ddl == 1 && ok7) ? idx : (int)ZENT;  // kd=7 lanes
            A7g[rz] = wf[idx];
        }

        const bool has3 = (khg == 1) || (khg == 2);
        short8 A3g[4] = {};
        if (has3) {
            const int kh3 = 2 * (khg - 1) + khp;            // 0..3 (3 = zero)
            const bool ok3 = ((unsigned)a3 < 10u) && (kh3 <= 2);
            const int cb3 = ok3 ? (W3BASE + kh3 * 10 + a3 - ddl * 30) : (int)ZENT;
            const int st3 = ok3 ? 30 : 0;
#pragma unroll
            for (int rz = 0; rz < 4; rz++) {
                int idx = cb3 + rz * st3;
                if (rz == 0) idx = (ddl == 0 && ok3) ? idx : (int)ZENT;
                if (rz == 3) idx = (ddl == 1 && ok3) ? idx : (int)ZENT;
                A3g[rz] = wf[idx];
            }
        }

        // kh=7 lanes (khg=3, khp=1) have zero A: clamp their B row to kh=6's.
        const int rowadd = (khg == 3) ? 6 : (2 * khg + khp);

#pragma unroll
        for (int zi = 0; zi < 14; zi++) {
            const int R = (zbase + zi) * HR + q + rowadd;
            const unsigned short* bp = &tile[R * RCOLS + 8 * kb];
            short8 B0 = *(const short8*)bp;
            short8 B1 = *(const short8*)(bp + 8);
#pragma unroll
            for (int ddg = 0; ddg < 4; ddg++) {
                const int rz = zi - 2 * ddg;
                if (rz >= 0 && rz < 8) {
                    acc7[ddg][0] = __builtin_amdgcn_mfma_f32_16x16x32_bf16(
                        A7g[rz], B0, acc7[ddg][0], 0, 0, 0);
                    acc7[ddg][1] = __builtin_amdgcn_mfma_f32_16x16x32_bf16(
                        A7g[rz], B1, acc7[ddg][1], 0, 0, 0);
                }
            }
            if (has3) {
#pragma unroll
                for (int ddg = 0; ddg < 4; ddg++) {
                    const int rz3 = zi - 2 - 2 * ddg;
                    if (rz3 >= 0 && rz3 < 4) {
                        acc3[ddg][0] = __builtin_amdgcn_mfma_f32_16x16x32_bf16(
                            A3g[rz3], B0, acc3[ddg][0], 0, 0, 0);
                        acc3[ddg][1] = __builtin_amdgcn_mfma_f32_16x16x32_bf16(
                            A3g[rz3], B1, acc3[ddg][1], 0, 0, 0);
                    }
                }
            }
        }
    }

    // ---- epilogue: C/D col n=q (h), row m=4p+r; residual x from LDS tile ----
#pragma unroll
    for (int ddg = 0; ddg < 4; ddg++) {
#pragma unroll
        for (int wh = 0; wh < 2; wh++) {
            const int d = d0 + zbase + 2 * ddg + khp;
            const int Rr = (zbase + 2 * ddg + khp + 3) * HR + (q + 3);
            uint2 u = *(const uint2*)&tile[Rr * RCOLS + 8 * wh + 4 * kb + 4];
            float xr[4];
            xr[0] = __builtin_bit_cast(float, u.x << 16);
            xr[1] = __builtin_bit_cast(float, u.x & 0xffff0000u);
            xr[2] = __builtin_bit_cast(float, u.y << 16);
            xr[3] = __builtin_bit_cast(float, u.y & 0xffff0000u);

            size_t off = ((size_t)(nb * Cc + c) * Dd + d) * (Hh * Ww)
                       + (size_t)(h0 + q) * Ww + w0 + 8 * wh + 4 * kb;
            float o[4];
#pragma unroll
            for (int r = 0; r < 4; r++) {
                float y7 = fmaxf(fmaf(acc7[ddg][wh][r], iv7, bb7), 0.f);
                float y3 = fmaxf(fmaf(acc3[ddg][wh][r], iv3, bb3), 0.f);
                float y1 = fmaxf(fmaf(xr[r], s1, bb1), 0.f);
                o[r] = fmaxf(xr[r] + y7 + y3 + y1, 0.f);
            }
            *(float4*)(out + off) = make_float4(o[0], o[1], o[2], o[3]);
        }
    }
}

extern "C" void kernel_launch(void* const* d_in, const int* in_sizes, int n_in,
                              void* d_out, int out_size, void* d_ws, size_t ws_size,
                              hipStream_t stream) {
    const float* x  = (const float*)d_in[0];
    const float* w7 = (const float*)d_in[1];
    const float* w3 = (const float*)d_in[2];
    const float* w1 = (const float*)d_in[3];
    const float* g7 = (const float*)d_in[4];
    const float* b7 = (const float*)d_in[5];
    const float* m7 = (const float*)d_in[6];
    const float* v7 = (const float*)d_in[7];
    const float* g3 = (const float*)d_in[8];
    const float* b3 = (const float*)d_in[9];
    const float* m3 = (const float*)d_in[10];
    const float* v3 = (const float*)d_in[11];
    const float* g1 = (const float*)d_in[12];
    const float* b1 = (const float*)d_in[13];
    const float* m1 = (const float*)d_in[14];
    const float* v1 = (const float*)d_in[15];
    float* out = (float*)d_out;

    dim3 grid(8192);   // 1-D; kernel swizzles to (slab, tile) XCD-contiguously
    dim3 block(256);
    hipLaunchKernelGGL(replk_mfma, grid, block, 0, stream,
                       x, w7, w3, w1, g7, b7, m7, v7, g3, b3, m3, v3,
                       g1, b1, m1, v1, out);
}

// Round 19
// 252.932 us; speedup vs baseline: 1.2382x; 1.0285x over previous
//
#include <hip/hip_runtime.h>
#include <hip/hip_bf16.h>

#define Dd 64
#define Hh 128
#define Ww 128
#define Cc 32

// block tile: 32d x 16h x 16w outputs; 512 threads = 8 waves.
// wave = (dgrp 0..3) x (whv 0..1): dgrp owns d-range [8*dgrp, 8*dgrp+8),
// whv owns one 8-wide w column half. Same LDS tile as the 256-thread r14
// design -> 3 blocks/CU resident = 24 waves/CU ceiling (was 12).
#define BD 32
#define BH 16
#define BW 16
#define ZR (BD + 6)        // 38 staged z-planes
#define HR (BH + 6)        // 22 staged h-rows
#define NR (ZR * HR)       // 836 rows
#define RCOLS 24           // bf16 cols per row; col = w - w0 + 4 (left halo 4)
#define BLKROW 3
#define NBLK (NR * BLKROW) // 2508 16B blocks to stage

// A-fragment table: 49 7^3-planes x 14 windows + 9 3^3-planes x 10 windows
// + 1 shared all-zero entry. 777 entries x 16B = 12432 B in LDS.
// Measured dead ends (do not revisit): r12 global wtab = L2 write storm;
// r13 slot rotation = worse banks; r15/r16 incremental staging = serialized
// loads; r15 inline-asm MFMA = scheduler fence; r17 full khg unroll = spill.
#define N7WIN 14
#define N3WIN 10
#define W3BASE (49 * N7WIN)          // 686
#define ZENT   (W3BASE + 9 * N3WIN) // 776
#define NENT   (ZENT + 1)           // 777

typedef __attribute__((ext_vector_type(8))) short short8;   // 8 bf16 (4 VGPR)
typedef __attribute__((ext_vector_type(4))) float floatx4;  // MFMA acc

static __device__ __forceinline__ unsigned short f2bf(float f) {
    unsigned u = __builtin_bit_cast(unsigned, f);
    u += 0x7fffu + ((u >> 16) & 1u);   // RNE
    return (unsigned short)(u >> 16);
}

static __device__ __forceinline__ unsigned pk2(float a, float b) {
    union { __hip_bfloat162 h; unsigned u; } cv;
    cv.h = __float22bfloat162_rn(make_float2(a, b));   // v_cvt_pk_bf16_f32
    return cv.u;
}

__global__ __launch_bounds__(512, 4) void replk_mfma(
    const float* __restrict__ x,
    const float* __restrict__ w7, const float* __restrict__ w3, const float* __restrict__ w1,
    const float* __restrict__ g7, const float* __restrict__ b7, const float* __restrict__ m7, const float* __restrict__ v7,
    const float* __restrict__ g3, const float* __restrict__ b3, const float* __restrict__ m3, const float* __restrict__ v3,
    const float* __restrict__ g1, const float* __restrict__ b1, const float* __restrict__ m1, const float* __restrict__ v1,
    float* __restrict__ out)
{
    __shared__ __align__(16) unsigned short tile[NR * RCOLS];  // 40128 B
    __shared__ __align__(16) unsigned short wtab[NENT * 8];    // 12432 B
    // 52560 raw -> 3 blocks/CU; 8 waves/block -> 24 waves/CU LDS ceiling

    const int tid = threadIdx.x;

    // XCD-aware swizzle: 8192 blocks, 8 XCDs, 1024 contiguous per XCD.
    const unsigned lid = blockIdx.x;
    const unsigned nl = (lid & 7u) * 1024u + (lid >> 3);
    const int bx = nl & 127;
    const int slab = nl >> 7;
    const int c = slab & 31;
    const int nb = slab >> 5;
    const int w0 = (bx & 7) * BW;
    const int h0 = ((bx >> 3) & 7) * BH;
    const int d0 = (bx >> 6) * BD;

    const float* xc = x + (size_t)(nb * Cc + c) * (Dd * Hh * Ww);

    // ---- build A-fragment table in LDS (r10/r11 layout, verified) ----
    for (int e = tid; e < NENT; e += 512) {
        unsigned short h8[8];
#pragma unroll
        for (int j = 0; j < 8; j++) {
            float v = 0.f;
            if (e < W3BASE) {
                int pl = e / N7WIN, a = e - pl * N7WIN;
                int t = a + j - 7;
                if ((unsigned)t < 7u)
                    v = w7[c * 343 + (pl / 7) * 49 + (pl % 7) * 7 + t];
            } else if (e < ZENT) {
                int e2 = e - W3BASE;
                int p3 = e2 / N3WIN, a = e2 - p3 * N3WIN;
                int t = a + j - 7;
                if ((unsigned)t < 3u)
                    v = w3[c * 27 + (p3 / 3) * 9 + (p3 % 3) * 3 + t];
            }
            h8[j] = f2bf(v);
        }
        uint4 pk;
        pk.x = (unsigned)h8[0] | ((unsigned)h8[1] << 16);
        pk.y = (unsigned)h8[2] | ((unsigned)h8[3] << 16);
        pk.z = (unsigned)h8[4] | ((unsigned)h8[5] << 16);
        pk.w = (unsigned)h8[6] | ((unsigned)h8[7] << 16);
        *(uint4*)&wtab[e * 8] = pk;
    }

    // ---- stage input tile fp32 -> bf16 (cvt_pk), division-based indices ----
    // (divisions keep the 5 iterations' addresses INDEPENDENT so all loads
    //  issue up front — incremental chains serialize them)
#pragma unroll
    for (int it = 0; it < 5; it++) {
        int s = tid + it * 512;
        if (s < NBLK) {
            int R = s / BLKROW, bl = s - R * BLKROW;
            int zi = R / HR, hr = R - zi * HR;
            int gz = d0 - 3 + zi, gh = h0 - 3 + hr, gw0 = w0 - 4 + bl * 8;
            float v[8];
#pragma unroll
            for (int j = 0; j < 8; j++) v[j] = 0.f;
            if ((unsigned)gz < (unsigned)Dd && (unsigned)gh < (unsigned)Hh) {
                const float* src = xc + ((size_t)gz * Hh + gh) * Ww + gw0;
                if (gw0 >= 0 && gw0 + 8 <= Ww) {
                    float4 a = *(const float4*)src;
                    float4 b = *(const float4*)(src + 4);
                    v[0] = a.x; v[1] = a.y; v[2] = a.z; v[3] = a.w;
                    v[4] = b.x; v[5] = b.y; v[6] = b.z; v[7] = b.w;
                } else {
#pragma unroll
                    for (int j = 0; j < 8; j++) {
                        int gw = gw0 + j;
                        if ((unsigned)gw < (unsigned)Ww) v[j] = src[j];
                    }
                }
            }
            uint4 pk;
            pk.x = pk2(v[0], v[1]);
            pk.y = pk2(v[2], v[3]);
            pk.z = pk2(v[4], v[5]);
            pk.w = pk2(v[6], v[7]);
            *(uint4*)&tile[R * RCOLS + bl * 8] = pk;
        }
    }

    // BN constants (wave-uniform)
    const float eps = 1e-5f;
    const float iv7 = g7[c] / sqrtf(v7[c] + eps);
    const float bb7 = b7[c] - m7[c] * iv7;
    const float iv3 = g3[c] / sqrtf(v3[c] + eps);
    const float bb3 = b3[c] - m3[c] * iv3;
    const float iv1 = g1[c] / sqrtf(v1[c] + eps);
    const float bb1 = b1[c] - m1[c] * iv1;
    const float s1 = w1[c] * iv1;

    __syncthreads();

    const int lane = tid & 63;
    const int wave = tid >> 6;        // 0..7
    const int whv = wave & 1;         // which 8-wide w half this wave owns
    const int dgrp = wave >> 1;       // which 8-d group
    const int q = lane & 15;          // m (A) / n (B,C,D)
    const int p = lane >> 4;
    const int khp = p >> 1;           // kh within pair
    const int kb  = p & 1;            // wc 16B-block
    const int ddl = q >> 3;           // d within M-pair (A side)
    const int mwq = q & 7;            // w within M (A side)
    const int zbase = dgrp * 8;       // wave's d-outputs [zbase, zbase+8)

    const int a7 = 8 * kb - mwq + 6;  // 7^3 window (valid [0,14))
    const int a3 = a7 - 2;            // 3^3 window (valid [0,10))
    const short8* wf = (const short8*)wtab;

    floatx4 acc7[4], acc3[4];
#pragma unroll
    for (int i = 0; i < 4; i++) { acc7[i] = (floatx4)0.f; acc3[i] = (floatx4)0.f; }

    // ---- khg-outer loop: kh-pairs {0,1}{2,3}{4,5}{6,-}; 3^3 shares B of khg 1,2;
    //      each wave computes only its whv column half (B = 1 short8/zi) ----
#pragma unroll 1
    for (int khg = 0; khg < 4; khg++) {
        const int kh = 2 * khg + khp;                       // 0..7 (7 = zero)
        const bool ok7 = ((unsigned)a7 < 14u) && (kh <= 6);
        const int cb7 = ok7 ? (kh * 14 + a7 - ddl * 98) : (int)ZENT;
        const int st7 = ok7 ? 98 : 0;
        short8 A7g[8];
#pragma unroll
        for (int rz = 0; rz < 8; rz++) {
            int idx = cb7 + rz * st7;
            if (rz == 0) idx = (ddl == 0 && ok7) ? idx : (int)ZENT;  // kd=-1 lanes
            if (rz == 7) idx = (ddl == 1 && ok7) ? idx : (int)ZENT;  // kd=7 lanes
            A7g[rz] = wf[idx];
        }

        const bool has3 = (khg == 1) || (khg == 2);
        short8 A3g[4] = {};
        if (has3) {
            const int kh3 = 2 * (khg - 1) + khp;            // 0..3 (3 = zero)
            const bool ok3 = ((unsigned)a3 < 10u) && (kh3 <= 2);
            const int cb3 = ok3 ? (W3BASE + kh3 * 10 + a3 - ddl * 30) : (int)ZENT;
            const int st3 = ok3 ? 30 : 0;
#pragma unroll
            for (int rz = 0; rz < 4; rz++) {
                int idx = cb3 + rz * st3;
                if (rz == 0) idx = (ddl == 0 && ok3) ? idx : (int)ZENT;
                if (rz == 3) idx = (ddl == 1 && ok3) ? idx : (int)ZENT;
                A3g[rz] = wf[idx];
            }
        }

        // kh=7 lanes (khg=3, khp=1) have zero A: clamp their B row to kh=6's.
        const int rowadd = (khg == 3) ? 6 : (2 * khg + khp);

#pragma unroll
        for (int zi = 0; zi < 14; zi++) {
            const int R = (zbase + zi) * HR + q + rowadd;
            short8 B = *(const short8*)&tile[R * RCOLS + 8 * kb + 8 * whv];
#pragma unroll
            for (int ddg = 0; ddg < 4; ddg++) {
                const int rz = zi - 2 * ddg;
                if (rz >= 0 && rz < 8)
                    acc7[ddg] = __builtin_amdgcn_mfma_f32_16x16x32_bf16(
                        A7g[rz], B, acc7[ddg], 0, 0, 0);
            }
            if (has3) {
#pragma unroll
                for (int ddg = 0; ddg < 4; ddg++) {
                    const int rz3 = zi - 2 - 2 * ddg;
                    if (rz3 >= 0 && rz3 < 4)
                        acc3[ddg] = __builtin_amdgcn_mfma_f32_16x16x32_bf16(
                            A3g[rz3], B, acc3[ddg], 0, 0, 0);
                }
            }
        }
    }

    // ---- epilogue: C/D col n=q (h), row m=4p+r; residual x from LDS tile ----
#pragma unroll
    for (int ddg = 0; ddg < 4; ddg++) {
        const int d = d0 + zbase + 2 * ddg + khp;
        const int Rr = (zbase + 2 * ddg + khp + 3) * HR + (q + 3);
        uint2 u = *(const uint2*)&tile[Rr * RCOLS + 8 * whv + 4 * kb + 4];
        float xr[4];
        xr[0] = __builtin_bit_cast(float, u.x << 16);
        xr[1] = __builtin_bit_cast(float, u.x & 0xffff0000u);
        xr[2] = __builtin_bit_cast(float, u.y << 16);
        xr[3] = __builtin_bit_cast(float, u.y & 0xffff0000u);

        size_t off = ((size_t)(nb * Cc + c) * Dd + d) * (Hh * Ww)
                   + (size_t)(h0 + q) * Ww + w0 + 8 * whv + 4 * kb;
        float o[4];
#pragma unroll
        for (int r = 0; r < 4; r++) {
            float y7 = fmaxf(fmaf(acc7[ddg][r], iv7, bb7), 0.f);
            float y3 = fmaxf(fmaf(acc3[ddg][r], iv3, bb3), 0.f);
            float y1 = fmaxf(fmaf(xr[r], s1, bb1), 0.f);
            o[r] = fmaxf(xr[r] + y7 + y3 + y1, 0.f);
        }
        *(float4*)(out + off) = make_float4(o[0], o[1], o[2], o[3]);
    }
}

extern "C" void kernel_launch(void* const* d_in, const int* in_sizes, int n_in,
                              void* d_out, int out_size, void* d_ws, size_t ws_size,
                              hipStream_t stream) {
    const float* x  = (const float*)d_in[0];
    const float* w7 = (const float*)d_in[1];
    const float* w3 = (const float*)d_in[2];
    const float* w1 = (const float*)d_in[3];
    const float* g7 = (const float*)d_in[4];
    const float* b7 = (const float*)d_in[5];
    const float* m7 = (const float*)d_in[6];
    const float* v7 = (const float*)d_in[7];
    const float* g3 = (const float*)d_in[8];
    const float* b3 = (const float*)d_in[9];
    const float* m3 = (const float*)d_in[10];
    const float* v3 = (const float*)d_in[11];
    const float* g1 = (const float*)d_in[12];
    const float* b1 = (const float*)d_in[13];
    const float* m1 = (const float*)d_in[14];
    const float* v1 = (const float*)d_in[15];
    float* out = (float*)d_out;

    dim3 grid(8192);   // 1-D; kernel swizzles to (slab, tile) XCD-contiguously
    dim3 block(512);   // 8 waves: 4 d-groups x 2 w-halves sharing one LDS tile
    hipLaunchKernelGGL(replk_mfma, grid, block, 0, stream,
                       x, w7, w3, w1, g7, b7, m7, v7, g3, b3, m3, v3,
                       g1, b1, m1, v1, out);
}

// Round 20
// 252.060 us; speedup vs baseline: 1.2425x; 1.0035x over previous
//
#include <hip/hip_runtime.h>
#include <hip/hip_bf16.h>

#define Dd 64
#define Hh 128
#define Ww 128
#define Cc 32

// block tile: 32d x 16h x 16w outputs; 512 threads = 8 waves.
// wave = (dgrp 0..3) x (whv 0..1). Same tile as r19; A-table shrunk to
// b64-pair entries so raw LDS 48256 -> 3 blocks/CU (24 waves) restores
// the occupancy the 512-thread design was built for (r19 sat at 2 blocks).
#define BD 32
#define BH 16
#define BW 16
#define ZR (BD + 6)        // 38 staged z-planes
#define HR (BH + 6)        // 22 staged h-rows
#define NR (ZR * HR)       // 836 rows
#define RCOLS 24           // bf16 cols per row; col = w - w0 + 4 (left halo 4)
#define BLKROW 3
#define NBLK (NR * BLKROW) // 2508 16B blocks to stage

// A-table, b64 half-window entries: E(pl,s) = 4 taps [wt[s+j-7], j=0..3].
// fragment(pl,a) = (E(pl,a), E(pl,a+4)) — two ds_read_b64, +32B imm offset.
// 7^3: 49 planes x 18 entries; 3^3: 9 x 14; zero region 8 entries.
// 1016 entries x 8B = 8128 B. Total LDS 40128+8128 = 48256 -> 3 blocks/CU.
// Dead ends (measured): r12 global wtab = L2 storm; r13 rotation = worse
// banks; r15/16 incremental staging = serialized loads; r15 inline-asm MFMA
// = sched fence; r17 full unroll = spill.
#define E7 18
#define E3N 14
#define W3B (49 * E7)            // 882
#define ZE  (W3B + 9 * E3N)      // 1008 (zero region 1008..1015)
#define NEnt (ZE + 8)            // 1016

typedef __attribute__((ext_vector_type(8))) short short8;   // 8 bf16 (4 VGPR)
typedef __attribute__((ext_vector_type(4))) float floatx4;  // MFMA acc

static __device__ __forceinline__ unsigned short f2bf(float f) {
    unsigned u = __builtin_bit_cast(unsigned, f);
    u += 0x7fffu + ((u >> 16) & 1u);   // RNE
    return (unsigned short)(u >> 16);
}

static __device__ __forceinline__ unsigned pk2(float a, float b) {
    union { __hip_bfloat162 h; unsigned u; } cv;
    cv.h = __float22bfloat162_rn(make_float2(a, b));   // v_cvt_pk_bf16_f32
    return cv.u;
}

// fragment = two aligned b64 reads at entry idx and idx+4 (same base, +32B)
static __device__ __forceinline__ short8 ldfrag(const unsigned short* wt, int idx) {
    uint2 lo = *(const uint2*)&wt[idx * 4];
    uint2 hi = *(const uint2*)&wt[idx * 4 + 16];
    union { unsigned u[4]; short8 s; } cv;
    cv.u[0] = lo.x; cv.u[1] = lo.y; cv.u[2] = hi.x; cv.u[3] = hi.y;
    return cv.s;
}

__global__ __launch_bounds__(512, 4) void replk_mfma(
    const float* __restrict__ x,
    const float* __restrict__ w7, const float* __restrict__ w3, const float* __restrict__ w1,
    const float* __restrict__ g7, const float* __restrict__ b7, const float* __restrict__ m7, const float* __restrict__ v7,
    const float* __restrict__ g3, const float* __restrict__ b3, const float* __restrict__ m3, const float* __restrict__ v3,
    const float* __restrict__ g1, const float* __restrict__ b1, const float* __restrict__ m1, const float* __restrict__ v1,
    float* __restrict__ out)
{
    __shared__ __align__(16) unsigned short tile[NR * RCOLS];  // 40128 B
    __shared__ __align__(16) unsigned short wtab[NEnt * 4];    // 8128 B

    const int tid = threadIdx.x;

    // XCD-aware swizzle: 8192 blocks, 8 XCDs, 1024 contiguous per XCD.
    const unsigned lid = blockIdx.x;
    const unsigned nl = (lid & 7u) * 1024u + (lid >> 3);
    const int bx = nl & 127;
    const int slab = nl >> 7;
    const int c = slab & 31;
    const int nb = slab >> 5;
    const int w0 = (bx & 7) * BW;
    const int h0 = ((bx >> 3) & 7) * BH;
    const int d0 = (bx >> 6) * BD;

    const float* xc = x + (size_t)(nb * Cc + c) * (Dd * Hh * Ww);

    // ---- build A half-window table (b64 entries) ----
    for (int e = tid; e < NEnt; e += 512) {
        unsigned short h4[4];
#pragma unroll
        for (int j = 0; j < 4; j++) {
            float v = 0.f;
            if (e < W3B) {
                int pl = e / E7, s = e - pl * E7;
                int t = s + j - 7;
                if ((unsigned)t < 7u)
                    v = w7[c * 343 + (pl / 7) * 49 + (pl % 7) * 7 + t];
            } else if (e < ZE) {
                int e2 = e - W3B;
                int p3 = e2 / E3N, s = e2 - p3 * E3N;
                int t = s + j - 7;
                if ((unsigned)t < 3u)
                    v = w3[c * 27 + (p3 / 3) * 9 + (p3 % 3) * 3 + t];
            }
            h4[j] = f2bf(v);
        }
        uint2 pk;
        pk.x = (unsigned)h4[0] | ((unsigned)h4[1] << 16);
        pk.y = (unsigned)h4[2] | ((unsigned)h4[3] << 16);
        *(uint2*)&wtab[e * 4] = pk;
    }

    // ---- stage input tile fp32 -> bf16 (cvt_pk), division-based indices ----
    // (divisions keep the 5 iterations' addresses INDEPENDENT so all loads
    //  issue up front — incremental chains serialize them)
#pragma unroll
    for (int it = 0; it < 5; it++) {
        int s = tid + it * 512;
        if (s < NBLK) {
            int R = s / BLKROW, bl = s - R * BLKROW;
            int zi = R / HR, hr = R - zi * HR;
            int gz = d0 - 3 + zi, gh = h0 - 3 + hr, gw0 = w0 - 4 + bl * 8;
            float v[8];
#pragma unroll
            for (int j = 0; j < 8; j++) v[j] = 0.f;
            if ((unsigned)gz < (unsigned)Dd && (unsigned)gh < (unsigned)Hh) {
                const float* src = xc + ((size_t)gz * Hh + gh) * Ww + gw0;
                if (gw0 >= 0 && gw0 + 8 <= Ww) {
                    float4 a = *(const float4*)src;
                    float4 b = *(const float4*)(src + 4);
                    v[0] = a.x; v[1] = a.y; v[2] = a.z; v[3] = a.w;
                    v[4] = b.x; v[5] = b.y; v[6] = b.z; v[7] = b.w;
                } else {
#pragma unroll
                    for (int j = 0; j < 8; j++) {
                        int gw = gw0 + j;
                        if ((unsigned)gw < (unsigned)Ww) v[j] = src[j];
                    }
                }
            }
            uint4 pk;
            pk.x = pk2(v[0], v[1]);
            pk.y = pk2(v[2], v[3]);
            pk.z = pk2(v[4], v[5]);
            pk.w = pk2(v[6], v[7]);
            *(uint4*)&tile[R * RCOLS + bl * 8] = pk;
        }
    }

    // BN constants (wave-uniform)
    const float eps = 1e-5f;
    const float iv7 = g7[c] / sqrtf(v7[c] + eps);
    const float bb7 = b7[c] - m7[c] * iv7;
    const float iv3 = g3[c] / sqrtf(v3[c] + eps);
    const float bb3 = b3[c] - m3[c] * iv3;
    const float iv1 = g1[c] / sqrtf(v1[c] + eps);
    const float bb1 = b1[c] - m1[c] * iv1;
    const float s1 = w1[c] * iv1;

    __syncthreads();

    const int lane = tid & 63;
    const int wave = tid >> 6;        // 0..7
    const int whv = wave & 1;         // which 8-wide w half this wave owns
    const int dgrp = wave >> 1;       // which 8-d group
    const int q = lane & 15;          // m (A) / n (B,C,D)
    const int p = lane >> 4;
    const int khp = p >> 1;           // kh within pair
    const int kb  = p & 1;            // wc 16B-block
    const int ddl = q >> 3;           // d within M-pair (A side)
    const int mwq = q & 7;            // w within M (A side)
    const int zbase = dgrp * 8;       // wave's d-outputs [zbase, zbase+8)

    const int a7 = 8 * kb - mwq + 6;  // 7^3 window (valid [0,14))
    const int a3 = a7 - 2;            // 3^3 window (valid [0,10))

    floatx4 acc7[4], acc3[4];
#pragma unroll
    for (int i = 0; i < 4; i++) { acc7[i] = (floatx4)0.f; acc3[i] = (floatx4)0.f; }

    // ---- khg-outer loop: kh-pairs {0,1}{2,3}{4,5}{6,-}; 3^3 shares B of khg 1,2;
    //      each wave computes only its whv column half (B = 1 short8/zi) ----
#pragma unroll 1
    for (int khg = 0; khg < 4; khg++) {
        const int kh = 2 * khg + khp;                       // 0..7 (7 = zero)
        const bool ok7 = ((unsigned)a7 < 14u) && (kh <= 6);
        // plane (kd*7+kh) base = plane*18; idx = (rz-ddl)*126 + kh*18 + a7
        const int cb7 = ok7 ? (kh * E7 + a7 - ddl * 126) : (int)ZE;
        const int st7 = ok7 ? 126 : 0;
        short8 A7g[8];
#pragma unroll
        for (int rz = 0; rz < 8; rz++) {
            int idx = cb7 + rz * st7;
            if (rz == 0) idx = (ddl == 0 && ok7) ? idx : (int)ZE;  // kd=-1 lanes
            if (rz == 7) idx = (ddl == 1 && ok7) ? idx : (int)ZE;  // kd=7 lanes
            A7g[rz] = ldfrag(wtab, idx);
        }

        const bool has3 = (khg == 1) || (khg == 2);
        short8 A3g[4] = {};
        if (has3) {
            const int kh3 = 2 * (khg - 1) + khp;            // 0..3 (3 = zero)
            const bool ok3 = ((unsigned)a3 < 10u) && (kh3 <= 2);
            const int cb3 = ok3 ? (W3B + kh3 * E3N + a3 - ddl * 42) : (int)ZE;
            const int st3 = ok3 ? 42 : 0;
#pragma unroll
            for (int rz = 0; rz < 4; rz++) {
                int idx = cb3 + rz * st3;
                if (rz == 0) idx = (ddl == 0 && ok3) ? idx : (int)ZE;
                if (rz == 3) idx = (ddl == 1 && ok3) ? idx : (int)ZE;
                A3g[rz] = ldfrag(wtab, idx);
            }
        }

        // kh=7 lanes (khg=3, khp=1) have zero A: clamp their B row to kh=6's.
        const int rowadd = (khg == 3) ? 6 : (2 * khg + khp);

#pragma unroll
        for (int zi = 0; zi < 14; zi++) {
            const int R = (zbase + zi) * HR + q + rowadd;
            short8 B = *(const short8*)&tile[R * RCOLS + 8 * kb + 8 * whv];
#pragma unroll
            for (int ddg = 0; ddg < 4; ddg++) {
                const int rz = zi - 2 * ddg;
                if (rz >= 0 && rz < 8)
                    acc7[ddg] = __builtin_amdgcn_mfma_f32_16x16x32_bf16(
                        A7g[rz], B, acc7[ddg], 0, 0, 0);
            }
            if (has3) {
#pragma unroll
                for (int ddg = 0; ddg < 4; ddg++) {
                    const int rz3 = zi - 2 - 2 * ddg;
                    if (rz3 >= 0 && rz3 < 4)
                        acc3[ddg] = __builtin_amdgcn_mfma_f32_16x16x32_bf16(
                            A3g[rz3], B, acc3[ddg], 0, 0, 0);
                }
            }
        }
    }

    // ---- epilogue: C/D col n=q (h), row m=4p+r; residual x from LDS tile ----
#pragma unroll
    for (int ddg = 0; ddg < 4; ddg++) {
        const int d = d0 + zbase + 2 * ddg + khp;
        const int Rr = (zbase + 2 * ddg + khp + 3) * HR + (q + 3);
        uint2 u = *(const uint2*)&tile[Rr * RCOLS + 8 * whv + 4 * kb + 4];
        float xr[4];
        xr[0] = __builtin_bit_cast(float, u.x << 16);
        xr[1] = __builtin_bit_cast(float, u.x & 0xffff0000u);
        xr[2] = __builtin_bit_cast(float, u.y << 16);
        xr[3] = __builtin_bit_cast(float, u.y & 0xffff0000u);

        size_t off = ((size_t)(nb * Cc + c) * Dd + d) * (Hh * Ww)
                   + (size_t)(h0 + q) * Ww + w0 + 8 * whv + 4 * kb;
        float o[4];
#pragma unroll
        for (int r = 0; r < 4; r++) {
            float y7 = fmaxf(fmaf(acc7[ddg][r], iv7, bb7), 0.f);
            float y3 = fmaxf(fmaf(acc3[ddg][r], iv3, bb3), 0.f);
            float y1 = fmaxf(fmaf(xr[r], s1, bb1), 0.f);
            o[r] = fmaxf(xr[r] + y7 + y3 + y1, 0.f);
        }
        *(float4*)(out + off) = make_float4(o[0], o[1], o[2], o[3]);
    }
}

extern "C" void kernel_launch(void* const* d_in, const int* in_sizes, int n_in,
                              void* d_out, int out_size, void* d_ws, size_t ws_size,
                              hipStream_t stream) {
    const float* x  = (const float*)d_in[0];
    const float* w7 = (const float*)d_in[1];
    const float* w3 = (const float*)d_in[2];
    const float* w1 = (const float*)d_in[3];
    const float* g7 = (const float*)d_in[4];
    const float* b7 = (const float*)d_in[5];
    const float* m7 = (const float*)d_in[6];
    const float* v7 = (const float*)d_in[7];
    const float* g3 = (const float*)d_in[8];
    const float* b3 = (const float*)d_in[9];
    const float* m3 = (const float*)d_in[10];
    const float* v3 = (const float*)d_in[11];
    const float* g1 = (const float*)d_in[12];
    const float* b1 = (const float*)d_in[13];
    const float* m1 = (const float*)d_in[14];
    const float* v1 = (const float*)d_in[15];
    float* out = (float*)d_out;

    dim3 grid(8192);   // 1-D; kernel swizzles to (slab, tile) XCD-contiguously
    dim3 block(512);   // 8 waves: 4 d-groups x 2 w-halves sharing one LDS tile
    hipLaunchKernelGGL(replk_mfma, grid, block, 0, stream,
                       x, w7, w3, w1, g7, b7, m7, v7, g3, b3, m3, v3,
                       g1, b1, m1, v1, out);
}